// Round 1
// baseline (1640.192 us; speedup 1.0000x reference)
//
#include <hip/hip_runtime.h>
#include <cstdint>

#define ALPHA 0.3f
#define NEG_FILL -200.0f

constexpr int Bc = 2, Vc = 50000, Tc = 3, Nc = 32;
constexpr int Fc = 128, FEc = 128, Uc = 128, Ec = 300000;
constexpr int TNc = Tc * Nc;     // 96
constexpr int BVc = Bc * Vc;     // 100000
constexpr int TEc = Tc * Ec;     // 900000

// ---------------------------------------------------------------------------
// K1: batched GEMM  xform[t,e,u] = edge_feats[t,e,:] @ W_dense[t][:,u] + b_dense[t][u]
//     + fused partial attention dot  dotx[t,e] = sum_u xform[t,e,u] * W_att[F+u]
// Block: 256 threads, tile = 64 edges x 128 u, K split into 2 chunks of 64.
// ---------------------------------------------------------------------------
__global__ __launch_bounds__(256) void k_gemm(
    const float* __restrict__ ef, const float* __restrict__ Wd,
    const float* __restrict__ bd, const float* __restrict__ Wa,
    float* __restrict__ xform, float* __restrict__ dotx)
{
    __shared__ float sW[64 * 128];   // [kk][u]
    __shared__ float sA[64 * 68];    // [e][kk], pad 68 (16B-aligned rows, 2-way max conflict)

    const int t   = blockIdx.y;
    const int e0  = blockIdx.x * 64;
    const int tid = threadIdx.x;
    const int tx  = tid & 15;        // u-group   (16 groups of 8 u)
    const int ty  = tid >> 4;        // edge-group (16 groups of 4 edges)
    const int ubase = tx * 8;

    const float* Ab = ef + ((size_t)t * Ec + e0) * FEc;
    const float* Wb = Wd + (size_t)t * FEc * Uc;

    float acc[4][8];
#pragma unroll
    for (int i = 0; i < 4; i++)
#pragma unroll
        for (int j = 0; j < 8; j++) acc[i][j] = 0.f;

    for (int kt = 0; kt < 2; kt++) {
        __syncthreads();
        // stage W chunk: 64 x 128 floats = 2048 float4
#pragma unroll
        for (int l = 0; l < 8; l++) {
            int i  = tid + l * 256;
            int kk = i >> 5, c4 = (i & 31) * 4;
            *(float4*)&sW[kk * 128 + c4] =
                *(const float4*)&Wb[(size_t)(kt * 64 + kk) * Uc + c4];
        }
        // stage A chunk: 64 edges x 64 k = 1024 float4
#pragma unroll
        for (int l = 0; l < 4; l++) {
            int i   = tid + l * 256;
            int row = i >> 4, c4 = (i & 15) * 4;
            if (e0 + row < Ec)
                *(float4*)&sA[row * 68 + c4] =
                    *(const float4*)&Ab[(size_t)row * FEc + kt * 64 + c4];
        }
        __syncthreads();
#pragma unroll 8
        for (int kk = 0; kk < 64; kk++) {
            float4 b0 = *(const float4*)&sW[kk * 128 + ubase];
            float4 b1 = *(const float4*)&sW[kk * 128 + ubase + 4];
            float bb[8] = {b0.x, b0.y, b0.z, b0.w, b1.x, b1.y, b1.z, b1.w};
            float aa[4];
#pragma unroll
            for (int i = 0; i < 4; i++) aa[i] = sA[(ty * 4 + i) * 68 + kk];
#pragma unroll
            for (int i = 0; i < 4; i++)
#pragma unroll
                for (int j = 0; j < 8; j++) acc[i][j] += aa[i] * bb[j];
        }
    }

    // epilogue: +bias, store xform, fused dot with W_att[F:], 16-lane shuffle reduce
    float bdv[8], wav[8];
#pragma unroll
    for (int j = 0; j < 8; j++) {
        bdv[j] = bd[t * Uc + ubase + j];
        wav[j] = Wa[Fc + ubase + j];
    }
#pragma unroll
    for (int i = 0; i < 4; i++) {
        const int e = e0 + ty * 4 + i;
        float vals[8];
        float p = 0.f;
#pragma unroll
        for (int j = 0; j < 8; j++) {
            vals[j] = acc[i][j] + bdv[j];
            p += vals[j] * wav[j];
        }
        if (e < Ec) {
            float* dst = xform + ((size_t)t * Ec + e) * Uc + ubase;
            *(float4*)&dst[0] = make_float4(vals[0], vals[1], vals[2], vals[3]);
            *(float4*)&dst[4] = make_float4(vals[4], vals[5], vals[6], vals[7]);
        }
#pragma unroll
        for (int m = 1; m < 16; m <<= 1) p += __shfl_xor(p, m);
        if (tx == 0 && e < Ec) dotx[t * Ec + e] = p;
    }
}

// ---------------------------------------------------------------------------
// K2: logits[t,e] = leaky_relu( features[b,v,:]·W_att[:F] + dotx + b_att )
// One wave per edge; features row (512B) is L3-resident.
// ---------------------------------------------------------------------------
__global__ __launch_bounds__(256) void k_logits(
    const int* __restrict__ eidx, const float* __restrict__ feat,
    const float* __restrict__ Wa, const float* __restrict__ ba,
    const float* __restrict__ dotx, float* __restrict__ logits)
{
    const int wv   = blockIdx.x * 4 + (threadIdx.x >> 6);
    const int lane = threadIdx.x & 63;
    if (wv >= TEc) return;
    const int b = eidx[wv * 3 + 0];
    const int v = eidx[wv * 3 + 1];
    const float* frow = feat + ((size_t)b * Vc + v) * Fc;
    float p = frow[lane] * Wa[lane] + frow[lane + 64] * Wa[lane + 64];
#pragma unroll
    for (int off = 32; off > 0; off >>= 1) p += __shfl_down(p, off);
    if (lane == 0) {
        float z = p + dotx[wv] + ba[0];
        logits[wv] = (z >= 0.f) ? z : ALPHA * z;
    }
}

// ---------------------------------------------------------------------------
// K3: deterministic last-write-wins scatter via atomicMax of edge key (t*E+e).
// keygrid is memset to -1 before this kernel.
// ---------------------------------------------------------------------------
__global__ __launch_bounds__(256) void k_scatter(
    const int* __restrict__ eidx, int* __restrict__ keyg)
{
    const int i = blockIdx.x * blockDim.x + threadIdx.x;
    if (i >= TEc) return;
    const int b = eidx[i * 3 + 0];
    const int v = eidx[i * 3 + 1];
    const int s = eidx[i * 3 + 2];
    const int t = i / Ec;
    const int idx = ((b * Vc + v) * Tc + t) * Nc + s;
    atomicMax(&keyg[idx], i);
}

// ---------------------------------------------------------------------------
// K4: per-vertex softmax stats over 96 slots (unset = NEG_FILL, exp underflows
// to 0 exactly). One wave per vertex.
// ---------------------------------------------------------------------------
__global__ __launch_bounds__(256) void k_softmax(
    const int* __restrict__ keyg, const float* __restrict__ logits,
    float* __restrict__ mOut, float* __restrict__ invden)
{
    const int wv   = blockIdx.x * 4 + (threadIdx.x >> 6);
    const int lane = threadIdx.x & 63;
    if (wv >= BVc) return;
    const int* row = keyg + (size_t)wv * TNc;
    int kA = row[lane];
    float l0 = (kA >= 0) ? logits[kA] : NEG_FILL;
    float l1 = NEG_FILL;
    if (lane < 32) {
        int kB = row[64 + lane];
        l1 = (kB >= 0) ? logits[kB] : NEG_FILL;
    }
    float m = fmaxf(l0, l1);
#pragma unroll
    for (int x = 1; x < 64; x <<= 1) m = fmaxf(m, __shfl_xor(m, x));
    float s = expf(l0 - m) + expf(l1 - m);
#pragma unroll
    for (int x = 1; x < 64; x <<= 1) s += __shfl_xor(s, x);
    if (lane == 0) {
        mOut[wv]   = m;
        invden[wv] = 1.0f / s;
    }
}

// ---------------------------------------------------------------------------
// K5: per-edge weighted scatter-add. Edge reads its slot's WINNING logit
// (matches reference gather of atts after collision-resolved set).
// ---------------------------------------------------------------------------
__global__ __launch_bounds__(256) void k_aggregate(
    const int* __restrict__ eidx, const int* __restrict__ keyg,
    const float* __restrict__ logits, const float* __restrict__ mIn,
    const float* __restrict__ invden, const float* __restrict__ xform,
    float* __restrict__ out)
{
    const int wv   = blockIdx.x * 4 + (threadIdx.x >> 6);
    const int lane = threadIdx.x & 63;
    if (wv >= TEc) return;
    const int b = eidx[wv * 3 + 0];
    const int v = eidx[wv * 3 + 1];
    const int s = eidx[wv * 3 + 2];
    const int t = wv / Ec;
    const int vtx = b * Vc + v;
    const int kwin = keyg[(size_t)vtx * TNc + t * Nc + s];
    const float att = expf(logits[kwin] - mIn[vtx]) * invden[vtx];
    const float* xr = xform + (size_t)wv * Uc;
    float* orow = out + (size_t)vtx * Uc;
    atomicAdd(&orow[lane],      xr[lane]      * att);
    atomicAdd(&orow[lane + 64], xr[lane + 64] * att);
}

// ---------------------------------------------------------------------------
// K6: multiply by degree = sum(adjacency >= 0) over (T,N). One wave per vertex.
// ---------------------------------------------------------------------------
__global__ __launch_bounds__(256) void k_scale(
    const int* __restrict__ adj, float* __restrict__ out)
{
    const int wv   = blockIdx.x * 4 + (threadIdx.x >> 6);
    const int lane = threadIdx.x & 63;
    if (wv >= BVc) return;
    const int* arow = adj + (size_t)wv * TNc;
    int c = (arow[lane] >= 0) ? 1 : 0;
    if (lane < 32) c += (arow[64 + lane] >= 0) ? 1 : 0;
#pragma unroll
    for (int x = 1; x < 64; x <<= 1) c += __shfl_xor(c, x);
    const float d = (float)c;
    float* orow = out + (size_t)wv * Uc;
    orow[lane]      *= d;
    orow[lane + 64] *= d;
}

// ---------------------------------------------------------------------------
extern "C" void kernel_launch(void* const* d_in, const int* in_sizes, int n_in,
                              void* d_out, int out_size, void* d_ws, size_t ws_size,
                              hipStream_t stream)
{
    const int*   adj  = (const int*)  d_in[0];  // (B,V,T,N)
    const float* feat = (const float*)d_in[1];  // (B,V,F)
    const int*   eidx = (const int*)  d_in[2];  // (T,E,3)
    const float* ef   = (const float*)d_in[3];  // (T,E,FE)
    const float* Wd   = (const float*)d_in[4];  // (T,FE,U)
    const float* bd   = (const float*)d_in[5];  // (T,U)
    const float* Wa   = (const float*)d_in[6];  // (F+U,1)
    const float* ba   = (const float*)d_in[7];  // (1,)
    float* out = (float*)d_out;

    char* ws = (char*)d_ws;
    float* xform  = (float*)ws;  ws += (size_t)TEc * Uc * sizeof(float);  // 460.8 MB
    float* dotx   = (float*)ws;  ws += (size_t)TEc * sizeof(float);       // 3.6 MB
    float* logits = (float*)ws;  ws += (size_t)TEc * sizeof(float);       // 3.6 MB
    int*   keyg   = (int*)  ws;  ws += (size_t)BVc * TNc * sizeof(int);   // 38.4 MB
    float* mArr   = (float*)ws;  ws += (size_t)BVc * sizeof(float);       // 0.4 MB
    float* invden = (float*)ws;  ws += (size_t)BVc * sizeof(float);       // 0.4 MB

    hipMemsetAsync(keyg, 0xFF, (size_t)BVc * TNc * sizeof(int), stream);  // -1
    hipMemsetAsync(out, 0, (size_t)out_size * sizeof(float), stream);

    dim3 g1((Ec + 63) / 64, Tc);
    k_gemm<<<g1, 256, 0, stream>>>(ef, Wd, bd, Wa, xform, dotx);
    k_logits<<<(TEc + 3) / 4, 256, 0, stream>>>(eidx, feat, Wa, ba, dotx, logits);
    k_scatter<<<(TEc + 255) / 256, 256, 0, stream>>>(eidx, keyg);
    k_softmax<<<(BVc + 3) / 4, 256, 0, stream>>>(keyg, logits, mArr, invden);
    k_aggregate<<<(TEc + 3) / 4, 256, 0, stream>>>(eidx, keyg, logits, mArr, invden, xform, out);
    k_scale<<<(BVc + 3) / 4, 256, 0, stream>>>(adj, out);
}

// Round 2
// 1004.830 us; speedup vs baseline: 1.6323x; 1.6323x over previous
//
#include <hip/hip_runtime.h>
#include <cstdint>

#define ALPHA 0.3f
#define NEG_FILL -200.0f

typedef unsigned short ushort_t;
typedef __attribute__((ext_vector_type(8))) short bf16x8;
typedef __attribute__((ext_vector_type(4))) float f32x4;

constexpr int Bc = 2, Vc = 50000, Tc = 3, Nc = 32;
constexpr int Fc = 128, FEc = 128, Uc = 128, Ec = 300000;
constexpr int TNc = Tc * Nc;     // 96
constexpr int BVc = Bc * Vc;     // 100000
constexpr int TEc = Tc * Ec;     // 900000
constexpr int CAP = 64;          // per-vertex edge bucket capacity (Poisson(9): P(>64)~1e-25)

__device__ __forceinline__ ushort_t f2bf(float f) {       // RNE float->bf16 bits
    unsigned u = __float_as_uint(f);
    return (ushort_t)((u + 0x7fffu + ((u >> 16) & 1u)) >> 16);
}
__device__ __forceinline__ float bf2f(ushort_t b) {
    return __uint_as_float(((unsigned)b) << 16);
}

// ---------------------------------------------------------------------------
// K0: W_dense -> bf16, transposed [u][k], XOR-swizzled in 8-elem granules so
// the GEMM can stage it to LDS with straight 16B copies. Layout per t: 2 k-chunks
// of 1024 granules; granule (u*8+pos) holds W[kt*64 + (pos^(u&7))*8 + j][u].
// ---------------------------------------------------------------------------
__global__ __launch_bounds__(256) void k_wprep(
    const float* __restrict__ Wd, ushort_t* __restrict__ Wt)
{
    const int g = blockIdx.x * 256 + threadIdx.x;
    if (g >= Tc * 2048) return;
    const int t = g >> 11, rem = g & 2047;
    const int kt = rem >> 10, gi = rem & 1023;
    const int u = gi >> 3, pos = gi & 7;
    const int kq = pos ^ (u & 7);
    const float* Ws = Wd + (size_t)t * FEc * Uc;
    bf16x8 val;
#pragma unroll
    for (int j = 0; j < 8; ++j)
        val[j] = (short)f2bf(Ws[(size_t)(kt * 64 + kq * 8 + j) * Uc + u]);
    *(bf16x8*)&Wt[(size_t)g * 8] = val;
}

// ---------------------------------------------------------------------------
// K1: MFMA bf16 GEMM. Tile 128 edges x 128 u, K=128 in 2 chunks of 64.
// 4 waves in 2x2; each wave: 4x4 grid of 16x16x32 MFMA tiles.
// LDS granule swizzle: granule kq of row r stored at position kq ^ (r&7)
// -> ds_read_b128 is 2-way-conflict max (free).
// Epilogue: +bias, bf16 store of xform, fused dotx = xform . W_att[F:].
// ---------------------------------------------------------------------------
__global__ __launch_bounds__(256) void k_gemm(
    const float* __restrict__ ef, const ushort_t* __restrict__ Wt,
    const float* __restrict__ bd, const float* __restrict__ Wa,
    ushort_t* __restrict__ xform, float* __restrict__ dotx)
{
    __shared__ ushort_t sA[128 * 64];  // 16 KB: 128 rows x 8 granules
    __shared__ ushort_t sW[128 * 64];  // 16 KB
    const int t   = blockIdx.y;
    const int e0  = blockIdx.x * 128;
    const int tid = threadIdx.x;
    const int wave = tid >> 6, lane = tid & 63;
    const int ln = lane & 15, quad = lane >> 4;
    const int m0 = (wave >> 1) * 64, n0 = (wave & 1) * 64;

    f32x4 acc[4][4];
#pragma unroll
    for (int i = 0; i < 4; ++i)
#pragma unroll
        for (int j = 0; j < 4; ++j)
#pragma unroll
            for (int r = 0; r < 4; ++r) acc[i][j][r] = 0.f;

    const float*    Ab = ef + ((size_t)t * Ec + e0) * FEc;
    const ushort_t* Wb = Wt + (size_t)t * 16384;

    for (int kt = 0; kt < 2; ++kt) {
        __syncthreads();
#pragma unroll
        for (int it = 0; it < 4; ++it) {
            const int g = tid + it * 256;
            const int row = g >> 3, pos = g & 7;
            const int kq = pos ^ (row & 7);
            bf16x8 val;
            if (e0 + row < Ec) {
                const float* s = Ab + (size_t)row * FEc + kt * 64 + kq * 8;
                float4 f0 = *(const float4*)s;
                float4 f1 = *(const float4*)(s + 4);
                val[0] = (short)f2bf(f0.x); val[1] = (short)f2bf(f0.y);
                val[2] = (short)f2bf(f0.z); val[3] = (short)f2bf(f0.w);
                val[4] = (short)f2bf(f1.x); val[5] = (short)f2bf(f1.y);
                val[6] = (short)f2bf(f1.z); val[7] = (short)f2bf(f1.w);
            } else {
#pragma unroll
                for (int q = 0; q < 8; ++q) val[q] = 0;
            }
            *(bf16x8*)&sA[(size_t)g * 8] = val;
            *(bf16x8*)&sW[(size_t)g * 8] = *(const bf16x8*)&Wb[(size_t)(kt * 1024 + g) * 8];
        }
        __syncthreads();
#pragma unroll
        for (int kk = 0; kk < 2; ++kk) {
            bf16x8 af[4], bfr[4];
            const int p = (kk * 4 + quad) ^ (ln & 7);
#pragma unroll
            for (int i = 0; i < 4; ++i) {
                const int row = m0 + i * 16 + ln;
                af[i] = *(const bf16x8*)&sA[(size_t)(row * 8 + p) * 8];
            }
#pragma unroll
            for (int j = 0; j < 4; ++j) {
                const int row = n0 + j * 16 + ln;
                bfr[j] = *(const bf16x8*)&sW[(size_t)(row * 8 + p) * 8];
            }
#pragma unroll
            for (int i = 0; i < 4; ++i)
#pragma unroll
                for (int j = 0; j < 4; ++j)
                    acc[i][j] = __builtin_amdgcn_mfma_f32_16x16x32_bf16(
                        af[i], bfr[j], acc[i][j], 0, 0, 0);
        }
    }

    // epilogue
    float bdv[4], wav[4];
#pragma unroll
    for (int j = 0; j < 4; ++j) {
        const int u = n0 + j * 16 + ln;
        bdv[j] = bd[t * Uc + u];
        wav[j] = Wa[Fc + u];
    }
#pragma unroll
    for (int i = 0; i < 4; ++i) {
#pragma unroll
        for (int r = 0; r < 4; ++r) {
            const int e = e0 + m0 + i * 16 + quad * 4 + r;   // D row = quad*4+reg
            if (e < Ec) {
                const size_t base = ((size_t)t * Ec + e) * Uc;
                float p = 0.f;
#pragma unroll
                for (int j = 0; j < 4; ++j) {
                    const float v = acc[i][j][r] + bdv[j];
                    xform[base + n0 + j * 16 + ln] = f2bf(v);  // D col = lane&15
                    p += v * wav[j];
                }
                p += __shfl_xor(p, 1); p += __shfl_xor(p, 2);
                p += __shfl_xor(p, 4); p += __shfl_xor(p, 8);
                if (ln == 0) atomicAdd(&dotx[t * Ec + e], p);  // two wn-halves combine
            }
        }
    }
}

// ---------------------------------------------------------------------------
// K2: per-VERTEX feature dot  fdot[bv] = features[bv,:] . W_att[:F]
// ---------------------------------------------------------------------------
__global__ __launch_bounds__(256) void k_fdot(
    const float* __restrict__ feat, const float* __restrict__ Wa,
    float* __restrict__ fdot)
{
    const int wv = blockIdx.x * 4 + (threadIdx.x >> 6);
    const int lane = threadIdx.x & 63;
    if (wv >= BVc) return;
    const float* fr = feat + (size_t)wv * Fc;
    float p = fr[lane] * Wa[lane] + fr[lane + 64] * Wa[lane + 64];
#pragma unroll
    for (int x = 1; x < 64; x <<= 1) p += __shfl_xor(p, x);
    if (lane == 0) fdot[wv] = p;
}

// ---------------------------------------------------------------------------
// K3: per-edge prep: logit = leaky(fdot+dotx+ba); last-write-wins slot key via
// atomicMax(edge id); bucket-fill per-vertex edge list (packed eid | s<<20).
// ---------------------------------------------------------------------------
__global__ __launch_bounds__(256) void k_prep(
    const int* __restrict__ eidx, const float* __restrict__ fdot,
    const float* __restrict__ dotx, const float* __restrict__ ba,
    float* __restrict__ logits, int* __restrict__ keyg,
    int* __restrict__ cnt, int* __restrict__ elist)
{
    const int i = blockIdx.x * 256 + threadIdx.x;
    if (i >= TEc) return;
    const int b = eidx[i * 3 + 0];
    const int v = eidx[i * 3 + 1];
    const int s = eidx[i * 3 + 2];
    const int t = i / Ec;
    const int vtx = b * Vc + v;
    const float z = fdot[vtx] + dotx[i] + ba[0];
    logits[i] = (z >= 0.f) ? z : ALPHA * z;
    atomicMax(&keyg[(size_t)vtx * TNc + t * Nc + s], i);
    const int pos = atomicAdd(&cnt[vtx], 1);
    if (pos < CAP) elist[(size_t)vtx * CAP + pos] = i | (s << 20);
}

// ---------------------------------------------------------------------------
// K4: fused per-vertex epilogue: softmax over 96 slots (winner logits, empty =
// NEG_FILL), degree from adjacency, gather bf16 xform rows of this vertex's
// edges, weighted accumulate, single write of out = acc * degree.
// Block = 128 threads (u dimension), one block per vertex.
// ---------------------------------------------------------------------------
__global__ __launch_bounds__(128) void k_vertex(
    const int* __restrict__ adj, const int* __restrict__ keyg,
    const float* __restrict__ logits, const int* __restrict__ cnt,
    const int* __restrict__ elist, const ushort_t* __restrict__ xform,
    float* __restrict__ out)
{
    const int vtx = blockIdx.x;
    const int tid = threadIdx.x;
    const int wave = tid >> 6, lane = tid & 63;
    __shared__ float att[TNc];
    __shared__ float redf[2];
    __shared__ float reds[2];
    __shared__ int   redi[2];

    float l = -1e30f;
    int dg = 0;
    if (tid < TNc) {
        const int k = keyg[(size_t)vtx * TNc + tid];
        l = (k >= 0) ? logits[k] : NEG_FILL;
        dg = (adj[(size_t)vtx * TNc + tid] >= 0) ? 1 : 0;
    }
    float m = l; int d = dg;
#pragma unroll
    for (int x = 1; x < 64; x <<= 1) {
        m = fmaxf(m, __shfl_xor(m, x));
        d += __shfl_xor(d, x);
    }
    if (lane == 0) { redf[wave] = m; redi[wave] = d; }
    __syncthreads();
    m = fmaxf(redf[0], redf[1]);
    const float degree = (float)(redi[0] + redi[1]);
    float e = (tid < TNc) ? expf(l - m) : 0.f;
    float sum = e;
#pragma unroll
    for (int x = 1; x < 64; x <<= 1) sum += __shfl_xor(sum, x);
    if (lane == 0) reds[wave] = sum;
    __syncthreads();
    const float invden = 1.0f / (reds[0] + reds[1]);
    if (tid < TNc) att[tid] = e * invden;
    __syncthreads();

    const int ne = min(cnt[vtx], CAP);
    float acc = 0.f;
    for (int it = 0; it < ne; ++it) {
        const int packed = elist[(size_t)vtx * CAP + it];
        const int eid = packed & 0xFFFFF;
        const int s   = packed >> 20;
        const float w = att[(eid / Ec) * Nc + s];
        acc += w * bf2f(xform[(size_t)eid * Uc + tid]);
    }
    out[(size_t)vtx * Uc + tid] = acc * degree;
}

// ---------------------------------------------------------------------------
extern "C" void kernel_launch(void* const* d_in, const int* in_sizes, int n_in,
                              void* d_out, int out_size, void* d_ws, size_t ws_size,
                              hipStream_t stream)
{
    const int*   adj  = (const int*)  d_in[0];  // (B,V,T,N)
    const float* feat = (const float*)d_in[1];  // (B,V,F)
    const int*   eidx = (const int*)  d_in[2];  // (T,E,3)
    const float* ef   = (const float*)d_in[3];  // (T,E,FE)
    const float* Wd   = (const float*)d_in[4];  // (T,FE,U)
    const float* bd   = (const float*)d_in[5];  // (T,U)
    const float* Wa   = (const float*)d_in[6];  // (F+U,1)
    const float* ba   = (const float*)d_in[7];  // (1,)
    float* out = (float*)d_out;

    char* ws = (char*)d_ws;
    ushort_t* xform  = (ushort_t*)ws; ws += (size_t)TEc * Uc * 2;        // 230.4 MB
    float*    dotx   = (float*)ws;    ws += (size_t)TEc * 4;             // 3.6 MB
    float*    logits = (float*)ws;    ws += (size_t)TEc * 4;             // 3.6 MB
    int*      keyg   = (int*)ws;      ws += (size_t)BVc * TNc * 4;       // 38.4 MB
    float*    fdot   = (float*)ws;    ws += (size_t)BVc * 4;             // 0.4 MB
    int*      cnt    = (int*)ws;      ws += (size_t)BVc * 4;             // 0.4 MB
    int*      elist  = (int*)ws;      ws += (size_t)BVc * CAP * 4;       // 25.6 MB
    ushort_t* Wt     = (ushort_t*)ws; ws += (size_t)Tc * 16384 * 2;      // 96 KB

    hipMemsetAsync(keyg, 0xFF, (size_t)BVc * TNc * 4, stream);
    hipMemsetAsync(cnt, 0, (size_t)BVc * 4, stream);
    hipMemsetAsync(dotx, 0, (size_t)TEc * 4, stream);

    k_wprep<<<(Tc * 2048 + 255) / 256, 256, 0, stream>>>(Wd, Wt);
    dim3 g1((Ec + 127) / 128, Tc);
    k_gemm<<<g1, 256, 0, stream>>>(ef, Wt, bd, Wa, xform, dotx);
    k_fdot<<<(BVc + 3) / 4, 256, 0, stream>>>(feat, Wa, fdot);
    k_prep<<<(TEc + 255) / 256, 256, 0, stream>>>(eidx, fdot, dotx, ba, logits, keyg, cnt, elist);
    k_vertex<<<BVc, 128, 0, stream>>>(adj, keyg, logits, cnt, elist, xform, out);
}